// Round 5
// baseline (1276.965 us; speedup 1.0000x reference)
//
#include <hip/hip_runtime.h>
#include <math.h>

// ---------------------------------------------------------------------------
// Temporal GNN. Round 5: barrier-free GEMM K-loop.
//  Block = 128 rows x 64 cols, 8 waves. B (hi+lo, all K=256, 64 cols) staged
//  to LDS ONCE via global_load_lds (XOR-swizzle n&7 -> conflict-free b128),
//  single barrier. A-frags stream global->VGPR with 1-chunk prefetch.
//  Aggregate: unroll 8. Pool: 4-wave split. splitB: merged launch.
// ---------------------------------------------------------------------------

typedef __attribute__((ext_vector_type(8))) short short8;   // 8 bf16
typedef __attribute__((ext_vector_type(4))) float floatx4;  // MFMA C/D

static __device__ __forceinline__ unsigned short f2bf(float f) {
    unsigned u = __float_as_uint(f);
    unsigned r = u + 0x7fff + ((u >> 16) & 1);   // RNE
    return (unsigned short)(r >> 16);
}
static __device__ __forceinline__ float bf2f(unsigned short s) {
    return __uint_as_float(((unsigned)s) << 16);
}

// async 16B/lane global -> LDS (dest = wave-uniform base + lane*16)
static __device__ __forceinline__ void gl_lds16(const void* g, void* l) {
    __builtin_amdgcn_global_load_lds(
        (const __attribute__((address_space(1))) unsigned int*)(g),
        (__attribute__((address_space(3))) unsigned int*)(l), 16, 0, 0);
}

// Split W[256][256] (k-major) into transposed bf16 planes Bt_hi/Bt_lo [n][k].
// grid (4,4,4): z = weight index.
__global__ void tg_splitB(const float* __restrict__ W0, const float* __restrict__ W1,
                          const float* __restrict__ W2, const float* __restrict__ W3,
                          unsigned short* __restrict__ H0, unsigned short* __restrict__ H1,
                          unsigned short* __restrict__ H2, unsigned short* __restrict__ H3,
                          unsigned short* __restrict__ L0, unsigned short* __restrict__ L1,
                          unsigned short* __restrict__ L2, unsigned short* __restrict__ L3)
{
    const float* Ws[4] = {W0, W1, W2, W3};
    unsigned short* Hs[4] = {H0, H1, H2, H3};
    unsigned short* Ls[4] = {L0, L1, L2, L3};
    const float* W = Ws[blockIdx.z];
    unsigned short* Bth = Hs[blockIdx.z];
    unsigned short* Btl = Ls[blockIdx.z];

    __shared__ float T[64][68];
    const int tk = blockIdx.x * 64, tn = blockIdx.y * 64;
    const int t = threadIdx.x;
#pragma unroll
    for (int j = 0; j < 4; ++j) {
        const int idx = t + 256 * j;
        const int k = idx >> 4, c4 = (idx & 15) * 4;
        const float4 v = *(const float4*)&W[(size_t)(tk + k) * 256 + tn + c4];
        T[k][c4] = v.x; T[k][c4 + 1] = v.y; T[k][c4 + 2] = v.z; T[k][c4 + 3] = v.w;
    }
    __syncthreads();
#pragma unroll
    for (int j = 0; j < 4; ++j) {
        const int idx = t + 256 * j;
        const int n = idx >> 4, q = (idx & 15) * 4;
        unsigned short hh[4], ll[4];
#pragma unroll
        for (int i = 0; i < 4; ++i) {
            const float f = T[q + i][n];
            hh[i] = f2bf(f);
            ll[i] = f2bf(f - bf2f(hh[i]));
        }
        uint2 hp, lp;
        hp.x = (unsigned)hh[0] | ((unsigned)hh[1] << 16);
        hp.y = (unsigned)hh[2] | ((unsigned)hh[3] << 16);
        lp.x = (unsigned)ll[0] | ((unsigned)ll[1] << 16);
        lp.y = (unsigned)ll[2] | ((unsigned)ll[3] << 16);
        *(uint2*)&Bth[(size_t)(tn + n) * 256 + tk + q] = hp;
        *(uint2*)&Btl[(size_t)(tn + n) * 256 + tk + q] = lp;
    }
}

// --- shared GEMM machinery: stage this block's B panel (64 cols x 256 k,
//     hi+lo) into LDS with n&7 XOR-swizzle on 16B k-groups.
#define STAGE_B()                                                              \
    do {                                                                       \
        _Pragma("unroll")                                                      \
        for (int i = 0; i < 4; ++i) {                                          \
            const int n0 = 8 * w + 2 * i;                                      \
            const int nl = n0 + (lane >> 5);                                   \
            const int d  = lane & 31;                                          \
            const size_t src = (size_t)(cg * 64 + nl) * 256                    \
                             + (size_t)((d ^ (nl & 7)) * 8);                   \
            gl_lds16(Bth + src, &sBh[n0 * 256]);                               \
            gl_lds16(Btl + src, &sBl[n0 * 256]);                               \
        }                                                                      \
    } while (0)

// ---- GCN GEMM: A = pre-split hi/lo bf16 planes; out = bf16 * rowscale.
__global__ __launch_bounds__(512, 4)
void tg_gemm_gcn(const unsigned short* __restrict__ Ahp,
                 const unsigned short* __restrict__ Alp,
                 const unsigned short* __restrict__ Bth,
                 const unsigned short* __restrict__ Btl,
                 const float* __restrict__ rowscale,
                 unsigned short* __restrict__ outBf)
{
    __shared__ unsigned short sBh[64 * 256], sBl[64 * 256];  // 32 KB each

    const int t = threadIdx.x;
    const int w = t >> 6, lane = t & 63;
    const int quad = lane >> 4, l16 = lane & 15;
    const int row0 = blockIdx.x * 128;
    const int cg = blockIdx.y;

    STAGE_B();

    floatx4 acc[4];
#pragma unroll
    for (int ct = 0; ct < 4; ++ct) acc[ct] = (floatx4){0.f, 0.f, 0.f, 0.f};

    const int arow = row0 + 16 * w + l16;
    const unsigned short* Ah0 = Ahp + (size_t)arow * 256 + quad * 8;
    const unsigned short* Al0 = Alp + (size_t)arow * 256 + quad * 8;

    __syncthreads();   // B panel resident (single barrier in whole kernel)

    short8 ah = *(const short8*)(Ah0);
    short8 al = *(const short8*)(Al0);
#pragma unroll
    for (int kc = 0; kc < 8; ++kc) {
        short8 ahn = ah, aln = al;
        if (kc < 7) {
            ahn = *(const short8*)(Ah0 + 32 * (kc + 1));
            aln = *(const short8*)(Al0 + 32 * (kc + 1));
        }
#pragma unroll
        for (int ct = 0; ct < 4; ++ct) {
            const int nl = ct * 16 + l16;
            const int slot = (kc * 4 + quad) ^ (nl & 7);
            const short8 bh = *(const short8*)&sBh[nl * 256 + slot * 8];
            const short8 bl = *(const short8*)&sBl[nl * 256 + slot * 8];
            acc[ct] = __builtin_amdgcn_mfma_f32_16x16x32_bf16(ah, bh, acc[ct], 0, 0, 0);
            acc[ct] = __builtin_amdgcn_mfma_f32_16x16x32_bf16(al, bh, acc[ct], 0, 0, 0);
            acc[ct] = __builtin_amdgcn_mfma_f32_16x16x32_bf16(ah, bl, acc[ct], 0, 0, 0);
        }
        ah = ahn; al = aln;
    }

#pragma unroll
    for (int i = 0; i < 4; ++i) {
        const int gr = row0 + 16 * w + quad * 4 + i;
        const float s = rowscale[gr];
#pragma unroll
        for (int ct = 0; ct < 4; ++ct) {
            const int gc = cg * 64 + ct * 16 + l16;
            outBf[(size_t)gr * 256 + gc] = f2bf(acc[ct][i] * s);
        }
    }
}

// ---- FT GEMM: A = x fp32, split on the fly; out = relu(A@B+bias) hi/lo.
__global__ __launch_bounds__(512, 4)
void tg_gemm_ft(const float* __restrict__ X,
                const unsigned short* __restrict__ Bth,
                const unsigned short* __restrict__ Btl,
                const float* __restrict__ bias,
                unsigned short* __restrict__ outHi,
                unsigned short* __restrict__ outLo, int M)
{
    __shared__ unsigned short sBh[64 * 256], sBl[64 * 256];

    const int t = threadIdx.x;
    const int w = t >> 6, lane = t & 63;
    const int quad = lane >> 4, l16 = lane & 15;
    const int row0 = blockIdx.x * 128;
    const int cg = blockIdx.y;

    STAGE_B();

    floatx4 acc[4];
#pragma unroll
    for (int ct = 0; ct < 4; ++ct) acc[ct] = (floatx4){0.f, 0.f, 0.f, 0.f};

    const int arow = row0 + 16 * w + l16;
    const bool ok = arow < M;
    const float* X0 = X + (size_t)arow * 256 + quad * 8;
    const float4 z4 = make_float4(0.f, 0.f, 0.f, 0.f);

    __syncthreads();

    float4 xa = ok ? *(const float4*)(X0) : z4;
    float4 xb = ok ? *(const float4*)(X0 + 4) : z4;
#pragma unroll
    for (int kc = 0; kc < 8; ++kc) {
        float4 xan = xa, xbn = xb;
        if (kc < 7) {
            xan = ok ? *(const float4*)(X0 + 32 * (kc + 1)) : z4;
            xbn = ok ? *(const float4*)(X0 + 32 * (kc + 1) + 4) : z4;
        }
        const float f[8] = {xa.x, xa.y, xa.z, xa.w, xb.x, xb.y, xb.z, xb.w};
        short8 ah, al;
#pragma unroll
        for (int i = 0; i < 8; ++i) {
            const unsigned short h = f2bf(f[i]);
            ah[i] = (short)h;
            al[i] = (short)f2bf(f[i] - bf2f(h));
        }
#pragma unroll
        for (int ct = 0; ct < 4; ++ct) {
            const int nl = ct * 16 + l16;
            const int slot = (kc * 4 + quad) ^ (nl & 7);
            const short8 bh = *(const short8*)&sBh[nl * 256 + slot * 8];
            const short8 bl = *(const short8*)&sBl[nl * 256 + slot * 8];
            acc[ct] = __builtin_amdgcn_mfma_f32_16x16x32_bf16(ah, bh, acc[ct], 0, 0, 0);
            acc[ct] = __builtin_amdgcn_mfma_f32_16x16x32_bf16(al, bh, acc[ct], 0, 0, 0);
            acc[ct] = __builtin_amdgcn_mfma_f32_16x16x32_bf16(ah, bl, acc[ct], 0, 0, 0);
        }
        xa = xan; xb = xbn;
    }

#pragma unroll
    for (int i = 0; i < 4; ++i) {
        const int gr = row0 + 16 * w + quad * 4 + i;
        if (gr >= M) continue;
#pragma unroll
        for (int ct = 0; ct < 4; ++ct) {
            const int gc = cg * 64 + ct * 16 + l16;
            float v = acc[ct][i] + bias[gc];
            v = fmaxf(v, 0.f);
            const unsigned short hi = f2bf(v);
            outHi[(size_t)gr * 256 + gc] = hi;
            outLo[(size_t)gr * 256 + gc] = f2bf(v - bf2f(hi));
        }
    }
}

// LayerNorm + PE over split hi/lo planes (in place). One wave per row.
__global__ void tg_ln_pe(unsigned short* __restrict__ hh, unsigned short* __restrict__ hl,
                         const float* __restrict__ g, const float* __restrict__ b, int N)
{
    const int gt = blockIdx.x * blockDim.x + threadIdx.x;
    const int row = gt >> 6;
    const int lane = threadIdx.x & 63;
    if (row >= N) return;
    const int c = lane * 4;
    unsigned short* hp = hh + (size_t)row * 256 + c;
    unsigned short* lp = hl + (size_t)row * 256 + c;
    const ushort4 vh = *(const ushort4*)hp;
    const ushort4 vl = *(const ushort4*)lp;
    const float v0 = bf2f(vh.x) + bf2f(vl.x);
    const float v1 = bf2f(vh.y) + bf2f(vl.y);
    const float v2 = bf2f(vh.z) + bf2f(vl.z);
    const float v3 = bf2f(vh.w) + bf2f(vl.w);
    float s = v0 + v1 + v2 + v3;
#pragma unroll
    for (int m = 1; m < 64; m <<= 1) s += __shfl_xor(s, m, 64);
    const float mu = s * (1.f / 256.f);
    const float d0 = v0 - mu, d1 = v1 - mu, d2 = v2 - mu, d3 = v3 - mu;
    float q = d0 * d0 + d1 * d1 + d2 * d2 + d3 * d3;
#pragma unroll
    for (int m = 1; m < 64; m <<= 1) q += __shfl_xor(q, m, 64);
    const float rstd = 1.f / sqrtf(q * (1.f / 256.f) + 1e-5f);

    const float4 gg = *(const float4*)&g[c];
    const float4 bb = *(const float4*)&b[c];
    const float cexp = -0.035977892078031970f;  // -log(10000)/256
    const float fn = (float)row;
    const float div0 = expf((float)c * cexp);
    const float div1 = expf((float)(c + 2) * cexp);
    const float a0 = fn * div0;
    const float a1 = fn * div1;
    float o[4];
    o[0] = d0 * rstd * gg.x + bb.x + sinf(a0);
    o[1] = d1 * rstd * gg.y + bb.y + cosf(a0);
    o[2] = d2 * rstd * gg.z + bb.z + sinf(a1);
    o[3] = d3 * rstd * gg.w + bb.w + cosf(a1);
    ushort4 oh, ol;
    oh.x = f2bf(o[0]); ol.x = f2bf(o[0] - bf2f(oh.x));
    oh.y = f2bf(o[1]); ol.y = f2bf(o[1] - bf2f(oh.y));
    oh.z = f2bf(o[2]); ol.z = f2bf(o[2] - bf2f(oh.z));
    oh.w = f2bf(o[3]); ol.w = f2bf(o[3] - bf2f(oh.w));
    *(ushort4*)hp = oh;
    *(ushort4*)lp = ol;
}

__global__ void tg_count(const int* __restrict__ dst, int* __restrict__ deg, int E)
{
    const int e = blockIdx.x * blockDim.x + threadIdx.x;
    if (e < E) atomicAdd(&deg[dst[e]], 1);
}

__global__ void tg_dinv(const int* __restrict__ deg, float* __restrict__ dinv, int N)
{
    const int i = blockIdx.x * blockDim.x + threadIdx.x;
    if (i < N) dinv[i] = 1.f / sqrtf((float)(deg[i] + 1));  // +1 self-loop
}

__global__ void tg_scan1(const int* __restrict__ cnt, int* __restrict__ out,
                         int* __restrict__ sums, int N)
{
    __shared__ int tmp[1024];
    const int t = threadIdx.x;
    const int gid = blockIdx.x * 1024 + t;
    const int v = (gid < N) ? cnt[gid] : 0;
    tmp[t] = v;
    __syncthreads();
    for (int o = 1; o < 1024; o <<= 1) {
        const int add = (t >= o) ? tmp[t - o] : 0;
        __syncthreads();
        tmp[t] += add;
        __syncthreads();
    }
    if (gid < N) out[gid] = tmp[t] - v;
    if (t == 1023) sums[blockIdx.x] = tmp[t];
}

__global__ void tg_scan2(int* __restrict__ sums, int nb)
{
    __shared__ int tmp[1024];
    const int t = threadIdx.x;
    const int v = (t < nb) ? sums[t] : 0;
    tmp[t] = v;
    __syncthreads();
    for (int o = 1; o < 1024; o <<= 1) {
        const int add = (t >= o) ? tmp[t - o] : 0;
        __syncthreads();
        tmp[t] += add;
        __syncthreads();
    }
    if (t < nb) sums[t] = tmp[t] - v;
}

__global__ void tg_scan3(int* __restrict__ rowptr, const int* __restrict__ offs,
                         int N, int E)
{
    const int gid = blockIdx.x * 1024 + threadIdx.x;
    if (gid < N) rowptr[gid] += offs[gid >> 10];
    else if (gid == N) rowptr[N] = E;
}

__global__ void tg_fill(const int* __restrict__ src, const int* __restrict__ dst,
                        const int* __restrict__ rowptr, int* __restrict__ cursor,
                        int* __restrict__ col, int E)
{
    const int e = blockIdx.x * blockDim.x + threadIdx.x;
    if (e >= E) return;
    const int d = dst[e];
    const int p = atomicAdd(&cursor[d], 1);
    col[rowptr[d] + p] = src[e];
}

// out = relu(dinv[i]*(hwp[i] + sum hwp[src]) + bias), hwp bf16, out split hi/lo.
// One wave per row, 4 channels/lane, neighbor loop unrolled x8.
__global__ void tg_aggregate_bf(const unsigned short* __restrict__ hwpb,
                                const int* __restrict__ rowptr, const int* __restrict__ col,
                                const float* __restrict__ dinv, const float* __restrict__ bias,
                                unsigned short* __restrict__ hh, unsigned short* __restrict__ hl,
                                int N)
{
    const int row = (blockIdx.x * blockDim.x + threadIdx.x) >> 6;
    if (row >= N) return;
    const int lane = threadIdx.x & 63;
    const int c = lane * 4;
    const unsigned short* base = hwpb + c;
    const ushort4 sv = *(const ushort4*)(base + (size_t)row * 256);
    float a0 = bf2f(sv.x), a1 = bf2f(sv.y), a2 = bf2f(sv.z), a3 = bf2f(sv.w);
    const int beg = rowptr[row], end = rowptr[row + 1];
    int p = beg;
    for (; p + 8 <= end; p += 8) {
        ushort4 v[8];
#pragma unroll
        for (int u = 0; u < 8; ++u)
            v[u] = *(const ushort4*)(base + (size_t)col[p + u] * 256);
#pragma unroll
        for (int u = 0; u < 8; ++u) {
            a0 += bf2f(v[u].x); a1 += bf2f(v[u].y);
            a2 += bf2f(v[u].z); a3 += bf2f(v[u].w);
        }
    }
    for (; p < end; ++p) {
        const ushort4 v = *(const ushort4*)(base + (size_t)col[p] * 256);
        a0 += bf2f(v.x); a1 += bf2f(v.y); a2 += bf2f(v.z); a3 += bf2f(v.w);
    }
    const float di = dinv[row];
    const float4 bb = *(const float4*)&bias[c];
    float o[4];
    o[0] = fmaxf(di * a0 + bb.x, 0.f);
    o[1] = fmaxf(di * a1 + bb.y, 0.f);
    o[2] = fmaxf(di * a2 + bb.z, 0.f);
    o[3] = fmaxf(di * a3 + bb.w, 0.f);
    ushort4 oh, ol;
    oh.x = f2bf(o[0]); ol.x = f2bf(o[0] - bf2f(oh.x));
    oh.y = f2bf(o[1]); ol.y = f2bf(o[1] - bf2f(oh.y));
    oh.z = f2bf(o[2]); ol.z = f2bf(o[2] - bf2f(oh.z));
    oh.w = f2bf(o[3]); ol.w = f2bf(o[3] - bf2f(oh.w));
    *(ushort4*)&hh[(size_t)row * 256 + c] = oh;
    *(ushort4*)&hl[(size_t)row * 256 + c] = ol;
}

__global__ void tg_ranges(const int* __restrict__ batch, int* __restrict__ starts,
                          int N, int G)
{
    const int g = blockIdx.x * blockDim.x + threadIdx.x;
    if (g > G) return;
    int lo = 0, hi = N;
    while (lo < hi) {
        const int mid = (lo + hi) >> 1;
        if (batch[mid] < g) lo = mid + 1; else hi = mid;
    }
    starts[g] = lo;
}

// Mean-pool: block per graph, 4 waves split rows, lane owns 4 channels.
__global__ void tg_pool(const unsigned short* __restrict__ hh,
                        const unsigned short* __restrict__ hl,
                        const int* __restrict__ starts, float* __restrict__ pooled, int G)
{
    __shared__ float sh[4][64][4];
    const int g = blockIdx.x;
    const int t = threadIdx.x;
    const int wv = t >> 6, lane = t & 63;
    const int c = lane * 4;
    const int beg = starts[g], end = starts[g + 1];
    float s0 = 0.f, s1 = 0.f, s2 = 0.f, s3 = 0.f;
    for (int r = beg + wv; r < end; r += 4) {
        const ushort4 vh = *(const ushort4*)&hh[(size_t)r * 256 + c];
        const ushort4 vl = *(const ushort4*)&hl[(size_t)r * 256 + c];
        s0 += bf2f(vh.x) + bf2f(vl.x);
        s1 += bf2f(vh.y) + bf2f(vl.y);
        s2 += bf2f(vh.z) + bf2f(vl.z);
        s3 += bf2f(vh.w) + bf2f(vl.w);
    }
    sh[wv][lane][0] = s0; sh[wv][lane][1] = s1;
    sh[wv][lane][2] = s2; sh[wv][lane][3] = s3;
    __syncthreads();
    if (t < 64) {
        const float inv = 1.f / fmaxf((float)(end - beg), 1.f);
        float4 o;
        o.x = (sh[0][t][0] + sh[1][t][0] + sh[2][t][0] + sh[3][t][0]) * inv;
        o.y = (sh[0][t][1] + sh[1][t][1] + sh[2][t][1] + sh[3][t][1]) * inv;
        o.z = (sh[0][t][2] + sh[1][t][2] + sh[2][t][2] + sh[3][t][2]) * inv;
        o.w = (sh[0][t][3] + sh[1][t][3] + sh[2][t][3] + sh[3][t][3]) * inv;
        *(float4*)&pooled[(size_t)g * 256 + t * 4] = o;
    }
}

__global__ void tg_mlp(const float* __restrict__ A, const float* __restrict__ B,
                       const float* __restrict__ bias, float* __restrict__ Cout,
                       int M, int K, int Nc, int do_relu)
{
    const int idx = blockIdx.x * blockDim.x + threadIdx.x;
    if (idx >= M * Nc) return;
    const int m = idx / Nc;
    const int n = idx - m * Nc;
    float acc = 0.f;
    for (int k = 0; k < K; ++k) acc += A[(size_t)m * K + k] * B[(size_t)k * Nc + n];
    acc += bias[n];
    Cout[idx] = do_relu ? fmaxf(acc, 0.f) : acc;
}

extern "C" void kernel_launch(void* const* d_in, const int* in_sizes, int n_in,
                              void* d_out, int out_size, void* d_ws, size_t ws_size,
                              hipStream_t stream)
{
    const float* x    = (const float*)d_in[0];
    const float* W_ft = (const float*)d_in[1];
    const float* b_ft = (const float*)d_in[2];
    const float* ln_g = (const float*)d_in[3];
    const float* ln_b = (const float*)d_in[4];
    const float* W_g[3] = {(const float*)d_in[5], (const float*)d_in[7], (const float*)d_in[9]};
    const float* b_g[3] = {(const float*)d_in[6], (const float*)d_in[8], (const float*)d_in[10]};
    const float* W_c0 = (const float*)d_in[11];
    const float* b_c0 = (const float*)d_in[12];
    const float* W_c1 = (const float*)d_in[13];
    const float* b_c1 = (const float*)d_in[14];
    const float* W_c2 = (const float*)d_in[15];
    const float* b_c2 = (const float*)d_in[16];
    const int*   edge  = (const int*)d_in[17];
    const int*   batch = (const int*)d_in[18];

    const int N    = in_sizes[18];        // 100000
    const int E    = in_sizes[17] / 2;    // 1600000
    const int Mpad = (N + 127) & ~127;    // 100096
    const int H2   = in_sizes[14];        // 128
    const int Cc   = in_sizes[15] / H2;   // 4
    const int G    = out_size / Cc;       // 512

    const int* srcI = edge;
    const int* dstI = edge + E;

    size_t off = 0;
    auto alloc = [&](size_t bytes) {
        char* p = (char*)d_ws + off;
        off = (off + bytes + 255) & ~(size_t)255;
        return p;
    };
    unsigned short* hh   = (unsigned short*)alloc((size_t)Mpad * 256 * 2);
    unsigned short* hl   = (unsigned short*)alloc((size_t)Mpad * 256 * 2);
    unsigned short* hwpb = (unsigned short*)alloc((size_t)Mpad * 256 * 2);
    float* dinv   = (float*)alloc((size_t)Mpad * 4);
    int*   deg    = (int*)alloc((size_t)Mpad * 4);
    int*   rowptr = (int*)alloc((size_t)(N + 1) * 4);
    int*   cursor = (int*)alloc((size_t)N * 4);
    int*   col    = (int*)alloc((size_t)E * 4);
    int*   bsums  = (int*)alloc(1024 * 4);
    int*   starts = (int*)alloc((size_t)(G + 1) * 4);
    float* pooled = (float*)alloc((size_t)G * 256 * 4);
    float* z0     = (float*)alloc((size_t)G * 256 * 4);
    float* z1     = (float*)alloc((size_t)G * H2 * 4);
    unsigned short* Bth[4];
    unsigned short* Btl[4];
    for (int i = 0; i < 4; ++i) {
        Bth[i] = (unsigned short*)alloc((size_t)256 * 256 * 2);
        Btl[i] = (unsigned short*)alloc((size_t)256 * 256 * 2);
    }
    (void)ws_size; (void)n_in;

    hipMemsetAsync(deg, 0, (size_t)Mpad * 4, stream);
    hipMemsetAsync(cursor, 0, (size_t)N * 4, stream);
    // zero pad rows of h planes (streamed as GEMM A for pad rows)
    hipMemsetAsync(hh + (size_t)N * 256, 0, (size_t)(Mpad - N) * 256 * 2, stream);
    hipMemsetAsync(hl + (size_t)N * 256, 0, (size_t)(Mpad - N) * 256 * 2, stream);

    // 0. pre-split all 4 weights (one launch)
    tg_splitB<<<dim3(4, 4, 4), dim3(256), 0, stream>>>(
        W_ft, W_g[0], W_g[1], W_g[2],
        Bth[0], Bth[1], Bth[2], Bth[3],
        Btl[0], Btl[1], Btl[2], Btl[3]);

    const dim3 GG(Mpad / 128, 4);
    // 1. feature transform -> h split planes
    tg_gemm_ft<<<GG, dim3(512), 0, stream>>>(x, Bth[0], Btl[0], b_ft, hh, hl, N);
    // 2. LayerNorm + positional encoding (in place on planes)
    tg_ln_pe<<<dim3((N + 3) / 4), dim3(256), 0, stream>>>(hh, hl, ln_g, ln_b, N);
    // 3. degrees + CSR build (rows = dst, cols = src)
    tg_count<<<dim3((E + 255) / 256), dim3(256), 0, stream>>>(dstI, deg, E);
    tg_dinv<<<dim3((Mpad + 255) / 256), dim3(256), 0, stream>>>(deg, dinv, Mpad);
    const int NB = (N + 1023) / 1024;
    tg_scan1<<<dim3(NB), dim3(1024), 0, stream>>>(deg, rowptr, bsums, N);
    tg_scan2<<<dim3(1), dim3(1024), 0, stream>>>(bsums, NB);
    tg_scan3<<<dim3((N + 1024) / 1024), dim3(1024), 0, stream>>>(rowptr, bsums, N, E);
    tg_fill<<<dim3((E + 255) / 256), dim3(256), 0, stream>>>(srcI, dstI, rowptr, cursor, col, E);
    // 4. GCN layers: hwpb = bf16((h@W)*dinv); h planes = relu(dinv*sum + b)
    for (int l = 0; l < 3; ++l) {
        tg_gemm_gcn<<<GG, dim3(512), 0, stream>>>(hh, hl, Bth[l + 1], Btl[l + 1], dinv, hwpb);
        tg_aggregate_bf<<<dim3((N + 3) / 4), dim3(256), 0, stream>>>(hwpb, rowptr, col, dinv,
                                                                     b_g[l], hh, hl, N);
    }
    // 5. per-graph mean pool
    tg_ranges<<<dim3((G + 256) / 256), dim3(256), 0, stream>>>(batch, starts, N, G);
    tg_pool<<<dim3(G), dim3(256), 0, stream>>>(hh, hl, starts, pooled, G);
    // 6. classifier MLP
    tg_mlp<<<dim3((G * 256 + 255) / 256), dim3(256), 0, stream>>>(pooled, W_c0, b_c0, z0, G, 256, 256, 1);
    tg_mlp<<<dim3((G * H2 + 255) / 256), dim3(256), 0, stream>>>(z0, W_c1, b_c1, z1, G, 256, H2, 1);
    tg_mlp<<<dim3((G * Cc + 255) / 256), dim3(256), 0, stream>>>(z1, W_c2, b_c2, (float*)d_out, G, H2, Cc, 0);
}

// Round 6
// 1254.479 us; speedup vs baseline: 1.0179x; 1.0179x over previous
//
#include <hip/hip_runtime.h>
#include <math.h>

// ---------------------------------------------------------------------------
// Temporal GNN. Round 6: split-bf16 GEMM recast as a plain K=768 bf16 GEMM
// in the m97 structure: A' = [Ah | Ah | Al] (chunk->plane map),
// B' = [Bh ; Bl ; Bh] (prebuilt, [n][768]). 128x128 tile, BK=64, 4 waves,
// 4x4 frags/wave, global_load_lds staging, XOR-swizzled LDS.
// ---------------------------------------------------------------------------

typedef __attribute__((ext_vector_type(8))) short short8;   // 8 bf16
typedef __attribute__((ext_vector_type(4))) float floatx4;  // MFMA C/D

static __device__ __forceinline__ unsigned short f2bf(float f) {
    unsigned u = __float_as_uint(f);
    unsigned r = u + 0x7fff + ((u >> 16) & 1);   // RNE
    return (unsigned short)(r >> 16);
}
static __device__ __forceinline__ float bf2f(unsigned short s) {
    return __uint_as_float(((unsigned)s) << 16);
}

// async 16B/lane global -> LDS (dest = wave-uniform base + lane*16)
static __device__ __forceinline__ void gl_lds16(const void* g, void* l) {
    __builtin_amdgcn_global_load_lds(
        (const __attribute__((address_space(1))) unsigned int*)(g),
        (__attribute__((address_space(3))) unsigned int*)(l), 16, 0, 0);
}

// Split W[256][256] (k-major) into Bt'[n][768] = [Bh | Bl | Bh] (transposed).
// grid (4,4,4): z = weight index.
__global__ void tg_splitB(const float* __restrict__ W0, const float* __restrict__ W1,
                          const float* __restrict__ W2, const float* __restrict__ W3,
                          unsigned short* __restrict__ B0, unsigned short* __restrict__ B1,
                          unsigned short* __restrict__ B2, unsigned short* __restrict__ B3)
{
    const float* Ws[4] = {W0, W1, W2, W3};
    unsigned short* Bs[4] = {B0, B1, B2, B3};
    const float* W = Ws[blockIdx.z];
    unsigned short* Bt = Bs[blockIdx.z];

    __shared__ float T[64][68];
    const int tk = blockIdx.x * 64, tn = blockIdx.y * 64;
    const int t = threadIdx.x;
#pragma unroll
    for (int j = 0; j < 4; ++j) {
        const int idx = t + 256 * j;
        const int k = idx >> 4, c4 = (idx & 15) * 4;
        const float4 v = *(const float4*)&W[(size_t)(tk + k) * 256 + tn + c4];
        T[k][c4] = v.x; T[k][c4 + 1] = v.y; T[k][c4 + 2] = v.z; T[k][c4 + 3] = v.w;
    }
    __syncthreads();
#pragma unroll
    for (int j = 0; j < 4; ++j) {
        const int idx = t + 256 * j;
        const int n = idx >> 4, q = (idx & 15) * 4;
        unsigned short hh[4], ll[4];
#pragma unroll
        for (int i = 0; i < 4; ++i) {
            const float f = T[q + i][n];
            hh[i] = f2bf(f);
            ll[i] = f2bf(f - bf2f(hh[i]));
        }
        uint2 hp, lp;
        hp.x = (unsigned)hh[0] | ((unsigned)hh[1] << 16);
        hp.y = (unsigned)hh[2] | ((unsigned)hh[3] << 16);
        lp.x = (unsigned)ll[0] | ((unsigned)ll[1] << 16);
        lp.y = (unsigned)ll[2] | ((unsigned)ll[3] << 16);
        unsigned short* row = Bt + (size_t)(tn + n) * 768;
        *(uint2*)&row[tk + q]       = hp;   // Bh
        *(uint2*)&row[256 + tk + q] = lp;   // Bl
        *(uint2*)&row[512 + tk + q] = hp;   // Bh (pairs with Al)
    }
}

// Pre-split x[M][256] fp32 -> xh/xl bf16 planes (zero pad rows >= N).
__global__ void tg_splitX(const float* __restrict__ x,
                          unsigned short* __restrict__ xh,
                          unsigned short* __restrict__ xl, int N, int Mpad)
{
    const int idx = blockIdx.x * 256 + threadIdx.x;
    const int r = idx >> 6, c4 = (idx & 63) * 4;
    if (r >= Mpad) return;
    ushort4 oh = {0, 0, 0, 0}, ol = {0, 0, 0, 0};
    if (r < N) {
        const float4 v = *(const float4*)&x[(size_t)r * 256 + c4];
        oh.x = f2bf(v.x); ol.x = f2bf(v.x - bf2f(oh.x));
        oh.y = f2bf(v.y); ol.y = f2bf(v.y - bf2f(oh.y));
        oh.z = f2bf(v.z); ol.z = f2bf(v.z - bf2f(oh.z));
        oh.w = f2bf(v.w); ol.w = f2bf(v.w - bf2f(oh.w));
    }
    *(ushort4*)&xh[(size_t)r * 256 + c4] = oh;
    *(ushort4*)&xl[(size_t)r * 256 + c4] = ol;
}

// m97-style GEMM: C[128x128 tile] = A'[M x 768] @ B'[768 x 128cols].
// A' chunks: c in [0,8) -> Ph, [8,12) -> Pl, k-offset (c&3)*64.
// B' physically [n][768], chunk k-offset c*64.
// mode 0 (FT): out = relu(acc+bias) -> hi/lo planes, rows < M only.
// mode 1 (GCN): out = bf16(acc * rowscale[row]) -> outHi.
__global__ __launch_bounds__(256, 3)
void tg_gemm(const unsigned short* __restrict__ Ph,
             const unsigned short* __restrict__ Pl,
             const unsigned short* __restrict__ Bt,
             const float* __restrict__ bias, const float* __restrict__ rowscale,
             unsigned short* __restrict__ outHi, unsigned short* __restrict__ outLo,
             int M, int mode)
{
    __shared__ unsigned short sA[128 * 64], sB[128 * 64];  // 16 KB each

    const int t = threadIdx.x;
    const int w = t >> 6, lane = t & 63;
    const int quad = lane >> 4, l16 = lane & 15;
    const int wr = w >> 1, wc = w & 1;
    const int row0 = blockIdx.x * 128;
    const int col0 = blockIdx.y * 128;

    floatx4 acc[4][4];
#pragma unroll
    for (int i = 0; i < 4; ++i)
#pragma unroll
        for (int j = 0; j < 4; ++j) acc[i][j] = (floatx4){0.f, 0.f, 0.f, 0.f};

    // staging decode: 8 lanes per row, slot = lane&7 holds source kg = slot^(row&7)
    const int srow = lane >> 3;                 // row within 8-row group
    const int kgx  = (lane & 7) ^ srow;         // swizzled source k-group
    const int rsw  = l16 & 7;                   // fragment-read swizzle key

#pragma unroll 1
    for (int c = 0; c < 12; ++c) {
        const unsigned short* Pa = (c < 8) ? Ph : Pl;
        const int ka = (c & 3) * 64;
        const int kb = c * 64;
        if (c) __syncthreads();
#pragma unroll
        for (int i = 0; i < 4; ++i) {
            const int r = w * 32 + i * 8;       // wave-uniform LDS row base
            gl_lds16(Pa + (size_t)(row0 + r + srow) * 256 + ka + kgx * 8, &sA[r * 64]);
            gl_lds16(Bt + (size_t)(col0 + r + srow) * 768 + kb + kgx * 8, &sB[r * 64]);
        }
        __syncthreads();

#pragma unroll
        for (int ks = 0; ks < 2; ++ks) {
            const int kq = ks * 4 + quad;
            short8 af[4], bf[4];
#pragma unroll
            for (int rt = 0; rt < 4; ++rt) {
                const int r = wr * 64 + rt * 16 + l16;
                af[rt] = *(const short8*)&sA[r * 64 + ((kq ^ rsw) * 8)];
            }
#pragma unroll
            for (int ct = 0; ct < 4; ++ct) {
                const int n = wc * 64 + ct * 16 + l16;
                bf[ct] = *(const short8*)&sB[n * 64 + ((kq ^ rsw) * 8)];
            }
#pragma unroll
            for (int ct = 0; ct < 4; ++ct)
#pragma unroll
                for (int rt = 0; rt < 4; ++rt)
                    acc[rt][ct] = __builtin_amdgcn_mfma_f32_16x16x32_bf16(
                        af[rt], bf[ct], acc[rt][ct], 0, 0, 0);
        }
    }

    if (mode == 1) {   // GCN: bf16(acc * rowscale)
#pragma unroll
        for (int rt = 0; rt < 4; ++rt) {
#pragma unroll
            for (int i = 0; i < 4; ++i) {
                const int gr = row0 + wr * 64 + rt * 16 + quad * 4 + i;
                const float s = rowscale[gr];
#pragma unroll
                for (int ct = 0; ct < 4; ++ct) {
                    const int gc = col0 + wc * 64 + ct * 16 + l16;
                    outHi[(size_t)gr * 256 + gc] = f2bf(acc[rt][ct][i] * s);
                }
            }
        }
    } else {           // FT: relu(acc+bias) -> hi/lo planes
#pragma unroll
        for (int rt = 0; rt < 4; ++rt) {
#pragma unroll
            for (int i = 0; i < 4; ++i) {
                const int gr = row0 + wr * 64 + rt * 16 + quad * 4 + i;
                if (gr >= M) continue;
#pragma unroll
                for (int ct = 0; ct < 4; ++ct) {
                    const int gc = col0 + wc * 64 + ct * 16 + l16;
                    float v = fmaxf(acc[rt][ct][i] + bias[gc], 0.f);
                    const unsigned short hi = f2bf(v);
                    outHi[(size_t)gr * 256 + gc] = hi;
                    outLo[(size_t)gr * 256 + gc] = f2bf(v - bf2f(hi));
                }
            }
        }
    }
}

// LayerNorm + PE over split hi/lo planes (in place). One wave per row.
__global__ void tg_ln_pe(unsigned short* __restrict__ hh, unsigned short* __restrict__ hl,
                         const float* __restrict__ g, const float* __restrict__ b, int N)
{
    const int gt = blockIdx.x * blockDim.x + threadIdx.x;
    const int row = gt >> 6;
    const int lane = threadIdx.x & 63;
    if (row >= N) return;
    const int c = lane * 4;
    unsigned short* hp = hh + (size_t)row * 256 + c;
    unsigned short* lp = hl + (size_t)row * 256 + c;
    const ushort4 vh = *(const ushort4*)hp;
    const ushort4 vl = *(const ushort4*)lp;
    const float v0 = bf2f(vh.x) + bf2f(vl.x);
    const float v1 = bf2f(vh.y) + bf2f(vl.y);
    const float v2 = bf2f(vh.z) + bf2f(vl.z);
    const float v3 = bf2f(vh.w) + bf2f(vl.w);
    float s = v0 + v1 + v2 + v3;
#pragma unroll
    for (int m = 1; m < 64; m <<= 1) s += __shfl_xor(s, m, 64);
    const float mu = s * (1.f / 256.f);
    const float d0 = v0 - mu, d1 = v1 - mu, d2 = v2 - mu, d3 = v3 - mu;
    float q = d0 * d0 + d1 * d1 + d2 * d2 + d3 * d3;
#pragma unroll
    for (int m = 1; m < 64; m <<= 1) q += __shfl_xor(q, m, 64);
    const float rstd = 1.f / sqrtf(q * (1.f / 256.f) + 1e-5f);

    const float4 gg = *(const float4*)&g[c];
    const float4 bb = *(const float4*)&b[c];
    const float cexp = -0.035977892078031970f;  // -log(10000)/256
    const float fn = (float)row;
    const float div0 = expf((float)c * cexp);
    const float div1 = expf((float)(c + 2) * cexp);
    const float a0 = fn * div0;
    const float a1 = fn * div1;
    float o[4];
    o[0] = d0 * rstd * gg.x + bb.x + sinf(a0);
    o[1] = d1 * rstd * gg.y + bb.y + cosf(a0);
    o[2] = d2 * rstd * gg.z + bb.z + sinf(a1);
    o[3] = d3 * rstd * gg.w + bb.w + cosf(a1);
    ushort4 oh, ol;
    oh.x = f2bf(o[0]); ol.x = f2bf(o[0] - bf2f(oh.x));
    oh.y = f2bf(o[1]); ol.y = f2bf(o[1] - bf2f(oh.y));
    oh.z = f2bf(o[2]); ol.z = f2bf(o[2] - bf2f(oh.z));
    oh.w = f2bf(o[3]); ol.w = f2bf(o[3] - bf2f(oh.w));
    *(ushort4*)hp = oh;
    *(ushort4*)lp = ol;
}

__global__ void tg_count(const int* __restrict__ dst, int* __restrict__ deg, int E)
{
    const int e = blockIdx.x * blockDim.x + threadIdx.x;
    if (e < E) atomicAdd(&deg[dst[e]], 1);
}

__global__ void tg_dinv(const int* __restrict__ deg, float* __restrict__ dinv, int N)
{
    const int i = blockIdx.x * blockDim.x + threadIdx.x;
    if (i < N) dinv[i] = 1.f / sqrtf((float)(deg[i] + 1));  // +1 self-loop
}

__global__ void tg_scan1(const int* __restrict__ cnt, int* __restrict__ out,
                         int* __restrict__ sums, int N)
{
    __shared__ int tmp[1024];
    const int t = threadIdx.x;
    const int gid = blockIdx.x * 1024 + t;
    const int v = (gid < N) ? cnt[gid] : 0;
    tmp[t] = v;
    __syncthreads();
    for (int o = 1; o < 1024; o <<= 1) {
        const int add = (t >= o) ? tmp[t - o] : 0;
        __syncthreads();
        tmp[t] += add;
        __syncthreads();
    }
    if (gid < N) out[gid] = tmp[t] - v;
    if (t == 1023) sums[blockIdx.x] = tmp[t];
}

__global__ void tg_scan2(int* __restrict__ sums, int nb)
{
    __shared__ int tmp[1024];
    const int t = threadIdx.x;
    const int v = (t < nb) ? sums[t] : 0;
    tmp[t] = v;
    __syncthreads();
    for (int o = 1; o < 1024; o <<= 1) {
        const int add = (t >= o) ? tmp[t - o] : 0;
        __syncthreads();
        tmp[t] += add;
        __syncthreads();
    }
    if (t < nb) sums[t] = tmp[t] - v;
}

__global__ void tg_scan3(int* __restrict__ rowptr, const int* __restrict__ offs,
                         int N, int E)
{
    const int gid = blockIdx.x * 1024 + threadIdx.x;
    if (gid < N) rowptr[gid] += offs[gid >> 10];
    else if (gid == N) rowptr[N] = E;
}

__global__ void tg_fill(const int* __restrict__ src, const int* __restrict__ dst,
                        const int* __restrict__ rowptr, int* __restrict__ cursor,
                        int* __restrict__ col, int E)
{
    const int e = blockIdx.x * blockDim.x + threadIdx.x;
    if (e >= E) return;
    const int d = dst[e];
    const int p = atomicAdd(&cursor[d], 1);
    col[rowptr[d] + p] = src[e];
}

// out = relu(dinv[i]*(hwp[i] + sum hwp[src]) + bias), hwp bf16, out split hi/lo.
__global__ void tg_aggregate_bf(const unsigned short* __restrict__ hwpb,
                                const int* __restrict__ rowptr, const int* __restrict__ col,
                                const float* __restrict__ dinv, const float* __restrict__ bias,
                                unsigned short* __restrict__ hh, unsigned short* __restrict__ hl,
                                int N)
{
    const int row = (blockIdx.x * blockDim.x + threadIdx.x) >> 6;
    if (row >= N) return;
    const int lane = threadIdx.x & 63;
    const int c = lane * 4;
    const unsigned short* base = hwpb + c;
    const ushort4 sv = *(const ushort4*)(base + (size_t)row * 256);
    float a0 = bf2f(sv.x), a1 = bf2f(sv.y), a2 = bf2f(sv.z), a3 = bf2f(sv.w);
    const int beg = rowptr[row], end = rowptr[row + 1];
    int p = beg;
    for (; p + 8 <= end; p += 8) {
        ushort4 v[8];
#pragma unroll
        for (int u = 0; u < 8; ++u)
            v[u] = *(const ushort4*)(base + (size_t)col[p + u] * 256);
#pragma unroll
        for (int u = 0; u < 8; ++u) {
            a0 += bf2f(v[u].x); a1 += bf2f(v[u].y);
            a2 += bf2f(v[u].z); a3 += bf2f(v[u].w);
        }
    }
    for (; p < end; ++p) {
        const ushort4 v = *(const ushort4*)(base + (size_t)col[p] * 256);
        a0 += bf2f(v.x); a1 += bf2f(v.y); a2 += bf2f(v.z); a3 += bf2f(v.w);
    }
    const float di = dinv[row];
    const float4 bb = *(const float4*)&bias[c];
    float o[4];
    o[0] = fmaxf(di * a0 + bb.x, 0.f);
    o[1] = fmaxf(di * a1 + bb.y, 0.f);
    o[2] = fmaxf(di * a2 + bb.z, 0.f);
    o[3] = fmaxf(di * a3 + bb.w, 0.f);
    ushort4 oh, ol;
    oh.x = f2bf(o[0]); ol.x = f2bf(o[0] - bf2f(oh.x));
    oh.y = f2bf(o[1]); ol.y = f2bf(o[1] - bf2f(oh.y));
    oh.z = f2bf(o[2]); ol.z = f2bf(o[2] - bf2f(oh.z));
    oh.w = f2bf(o[3]); ol.w = f2bf(o[3] - bf2f(oh.w));
    *(ushort4*)&hh[(size_t)row * 256 + c] = oh;
    *(ushort4*)&hl[(size_t)row * 256 + c] = ol;
}

__global__ void tg_ranges(const int* __restrict__ batch, int* __restrict__ starts,
                          int N, int G)
{
    const int g = blockIdx.x * blockDim.x + threadIdx.x;
    if (g > G) return;
    int lo = 0, hi = N;
    while (lo < hi) {
        const int mid = (lo + hi) >> 1;
        if (batch[mid] < g) lo = mid + 1; else hi = mid;
    }
    starts[g] = lo;
}

// Mean-pool: block per graph, 4 waves split rows, lane owns 4 channels.
__global__ void tg_pool(const unsigned short* __restrict__ hh,
                        const unsigned short* __restrict__ hl,
                        const int* __restrict__ starts, float* __restrict__ pooled, int G)
{
    __shared__ float sh[4][64][4];
    const int g = blockIdx.x;
    const int t = threadIdx.x;
    const int wv = t >> 6, lane = t & 63;
    const int c = lane * 4;
    const int beg = starts[g], end = starts[g + 1];
    float s0 = 0.f, s1 = 0.f, s2 = 0.f, s3 = 0.f;
    for (int r = beg + wv; r < end; r += 4) {
        const ushort4 vh = *(const ushort4*)&hh[(size_t)r * 256 + c];
        const ushort4 vl = *(const ushort4*)&hl[(size_t)r * 256 + c];
        s0 += bf2f(vh.x) + bf2f(vl.x);
        s1 += bf2f(vh.y) + bf2f(vl.y);
        s2 += bf2f(vh.z) + bf2f(vl.z);
        s3 += bf2f(vh.w) + bf2f(vl.w);
    }
    sh[wv][lane][0] = s0; sh[wv][lane][1] = s1;
    sh[wv][lane][2] = s2; sh[wv][lane][3] = s3;
    __syncthreads();
    if (t < 64) {
        const float inv = 1.f / fmaxf((float)(end - beg), 1.f);
        float4 o;
        o.x = (sh[0][t][0] + sh[1][t][0] + sh[2][t][0] + sh[3][t][0]) * inv;
        o.y = (sh[0][t][1] + sh[1][t][1] + sh[2][t][1] + sh[3][t][1]) * inv;
        o.z = (sh[0][t][2] + sh[1][t][2] + sh[2][t][2] + sh[3][t][2]) * inv;
        o.w = (sh[0][t][3] + sh[1][t][3] + sh[2][t][3] + sh[3][t][3]) * inv;
        *(float4*)&pooled[(size_t)g * 256 + t * 4] = o;
    }
}

__global__ void tg_mlp(const float* __restrict__ A, const float* __restrict__ B,
                       const float* __restrict__ bias, float* __restrict__ Cout,
                       int M, int K, int Nc, int do_relu)
{
    const int idx = blockIdx.x * blockDim.x + threadIdx.x;
    if (idx >= M * Nc) return;
    const int m = idx / Nc;
    const int n = idx - m * Nc;
    float acc = 0.f;
    for (int k = 0; k < K; ++k) acc += A[(size_t)m * K + k] * B[(size_t)k * Nc + n];
    acc += bias[n];
    Cout[idx] = do_relu ? fmaxf(acc, 0.f) : acc;
}

extern "C" void kernel_launch(void* const* d_in, const int* in_sizes, int n_in,
                              void* d_out, int out_size, void* d_ws, size_t ws_size,
                              hipStream_t stream)
{
    const float* x    = (const float*)d_in[0];
    const float* W_ft = (const float*)d_in[1];
    const float* b_ft = (const float*)d_in[2];
    const float* ln_g = (const float*)d_in[3];
    const float* ln_b = (const float*)d_in[4];
    const float* W_g[3] = {(const float*)d_in[5], (const float*)d_in[7], (const float*)d_in[9]};
    const float* b_g[3] = {(const float*)d_in[6], (const float*)d_in[8], (const float*)d_in[10]};
    const float* W_c0 = (const float*)d_in[11];
    const float* b_c0 = (const float*)d_in[12];
    const float* W_c1 = (const float*)d_in[13];
    const float* b_c1 = (const float*)d_in[14];
    const float* W_c2 = (const float*)d_in[15];
    const float* b_c2 = (const float*)d_in[16];
    const int*   edge  = (const int*)d_in[17];
    const int*   batch = (const int*)d_in[18];

    const int N    = in_sizes[18];        // 100000
    const int E    = in_sizes[17] / 2;    // 1600000
    const int Mpad = (N + 127) & ~127;    // 100096
    const int H2   = in_sizes[14];        // 128
    const int Cc   = in_sizes[15] / H2;   // 4
    const int G    = out_size / Cc;       // 512

    const int* srcI = edge;
    const int* dstI = edge + E;

    size_t off = 0;
    auto alloc = [&](size_t bytes) {
        char* p = (char*)d_ws + off;
        off = (off + bytes + 255) & ~(size_t)255;
        return p;
    };
    unsigned short* hh   = (unsigned short*)alloc((size_t)Mpad * 256 * 2);
    unsigned short* hl   = (unsigned short*)alloc((size_t)Mpad * 256 * 2);
    unsigned short* hwpb = (unsigned short*)alloc((size_t)Mpad * 256 * 2); // aliases xh
    unsigned short* xl   = (unsigned short*)alloc((size_t)Mpad * 256 * 2);
    unsigned short* xh   = hwpb;  // x hi-plane lives in hwpb until FT GEMM done
    float* dinv   = (float*)alloc((size_t)Mpad * 4);
    int*   deg    = (int*)alloc((size_t)Mpad * 4);
    int*   rowptr = (int*)alloc((size_t)(N + 1) * 4);
    int*   cursor = (int*)alloc((size_t)N * 4);
    int*   col    = (int*)alloc((size_t)E * 4);
    int*   bsums  = (int*)alloc(1024 * 4);
    int*   starts = (int*)alloc((size_t)(G + 1) * 4);
    float* pooled = (float*)alloc((size_t)G * 256 * 4);
    float* z0     = (float*)alloc((size_t)G * 256 * 4);
    float* z1     = (float*)alloc((size_t)G * H2 * 4);
    unsigned short* Bt[4];
    for (int i = 0; i < 4; ++i)
        Bt[i] = (unsigned short*)alloc((size_t)256 * 768 * 2);
    (void)ws_size; (void)n_in;

    hipMemsetAsync(deg, 0, (size_t)Mpad * 4, stream);
    hipMemsetAsync(cursor, 0, (size_t)N * 4, stream);
    // zero pad rows of h planes (read by GCN GEMM A staging; FT epilogue skips them)
    hipMemsetAsync(hh + (size_t)N * 256, 0, (size_t)(Mpad - N) * 256 * 2, stream);
    hipMemsetAsync(hl + (size_t)N * 256, 0, (size_t)(Mpad - N) * 256 * 2, stream);

    // 0. weight prep + x split
    tg_splitB<<<dim3(4, 4, 4), dim3(256), 0, stream>>>(
        W_ft, W_g[0], W_g[1], W_g[2], Bt[0], Bt[1], Bt[2], Bt[3]);
    tg_splitX<<<dim3(Mpad / 4), dim3(256), 0, stream>>>(x, xh, xl, N, Mpad);

    const dim3 GG(Mpad / 128, 2);
    // 1. feature transform -> h split planes
    tg_gemm<<<GG, dim3(256), 0, stream>>>(xh, xl, Bt[0], b_ft, nullptr, hh, hl, N, 0);
    // 2. LayerNorm + positional encoding (in place on planes)
    tg_ln_pe<<<dim3((N + 3) / 4), dim3(256), 0, stream>>>(hh, hl, ln_g, ln_b, N);
    // 3. degrees + CSR build (rows = dst, cols = src)
    tg_count<<<dim3((E + 255) / 256), dim3(256), 0, stream>>>(dstI, deg, E);
    tg_dinv<<<dim3((Mpad + 255) / 256), dim3(256), 0, stream>>>(deg, dinv, Mpad);
    const int NB = (N + 1023) / 1024;
    tg_scan1<<<dim3(NB), dim3(1024), 0, stream>>>(deg, rowptr, bsums, N);
    tg_scan2<<<dim3(1), dim3(1024), 0, stream>>>(bsums, NB);
    tg_scan3<<<dim3((N + 1024) / 1024), dim3(1024), 0, stream>>>(rowptr, bsums, N, E);
    tg_fill<<<dim3((E + 255) / 256), dim3(256), 0, stream>>>(srcI, dstI, rowptr, cursor, col, E);
    // 4. GCN layers: hwpb = bf16((h@W)*dinv); h planes = relu(dinv*sum + b)
    for (int l = 0; l < 3; ++l) {
        tg_gemm<<<GG, dim3(256), 0, stream>>>(hh, hl, Bt[l + 1], nullptr, dinv,
                                              hwpb, nullptr, Mpad, 1);
        tg_aggregate_bf<<<dim3((N + 3) / 4), dim3(256), 0, stream>>>(hwpb, rowptr, col, dinv,
                                                                     b_g[l], hh, hl, N);
    }
    // 5. per-graph mean pool
    tg_ranges<<<dim3((G + 256) / 256), dim3(256), 0, stream>>>(batch, starts, N, G);
    tg_pool<<<dim3(G), dim3(256), 0, stream>>>(hh, hl, starts, pooled, G);
    // 6. classifier MLP
    tg_mlp<<<dim3((G * 256 + 255) / 256), dim3(256), 0, stream>>>(pooled, W_c0, b_c0, z0, G, 256, 256, 1);
    tg_mlp<<<dim3((G * H2 + 255) / 256), dim3(256), 0, stream>>>(z0, W_c1, b_c1, z1, G, 256, H2, 1);
    tg_mlp<<<dim3((G * Cc + 255) / 256), dim3(256), 0, stream>>>(z1, W_c2, b_c2, (float*)d_out, G, H2, Cc, 0);
}

// Round 7
// 1194.080 us; speedup vs baseline: 1.0694x; 1.0506x over previous
//
#include <hip/hip_runtime.h>
#include <math.h>

// ---------------------------------------------------------------------------
// Temporal GNN. Round 7: bf16 -> fp16 everywhere (4x smaller rounding error
// at same byte cost, same MFMA rate). h carried as a SINGLE f16 plane for
// GCN GEMMs (K'=512: Ah*Bh + Ah*Bl); FT keeps split-f16 x (K'=768) and
// writes an f16 hi/lo pair consumed by LN, which emits the single plane.
// GEMM structure = round 6 (128x128 tile, BK=64, global_load_lds, swizzle).
// ---------------------------------------------------------------------------

typedef __attribute__((ext_vector_type(8))) _Float16 half8;  // MFMA A/B frag
typedef __attribute__((ext_vector_type(4))) float floatx4;   // MFMA C/D

union HU { _Float16 h; unsigned short u; };

static __device__ __forceinline__ unsigned short f2h(float f) {
    HU x; x.h = (_Float16)f; return x.u;          // v_cvt_f16_f32 (RNE)
}
static __device__ __forceinline__ float h2f(unsigned short s) {
    HU x; x.u = s; return (float)x.h;
}

// async 16B/lane global -> LDS (dest = wave-uniform base + lane*16)
static __device__ __forceinline__ void gl_lds16(const void* g, void* l) {
    __builtin_amdgcn_global_load_lds(
        (const __attribute__((address_space(1))) unsigned int*)(g),
        (__attribute__((address_space(3))) unsigned int*)(l), 16, 0, 0);
}

// Split W[256][256] (k-major) into Bt'[n][768] = [Bh | Bl | Bh] f16 (transposed).
// grid (4,4,4): z = weight index. GCN GEMMs use only the first 512 columns.
__global__ void tg_splitB(const float* __restrict__ W0, const float* __restrict__ W1,
                          const float* __restrict__ W2, const float* __restrict__ W3,
                          unsigned short* __restrict__ B0, unsigned short* __restrict__ B1,
                          unsigned short* __restrict__ B2, unsigned short* __restrict__ B3)
{
    const float* Ws[4] = {W0, W1, W2, W3};
    unsigned short* Bs[4] = {B0, B1, B2, B3};
    const float* W = Ws[blockIdx.z];
    unsigned short* Bt = Bs[blockIdx.z];

    __shared__ float T[64][68];
    const int tk = blockIdx.x * 64, tn = blockIdx.y * 64;
    const int t = threadIdx.x;
#pragma unroll
    for (int j = 0; j < 4; ++j) {
        const int idx = t + 256 * j;
        const int k = idx >> 4, c4 = (idx & 15) * 4;
        const float4 v = *(const float4*)&W[(size_t)(tk + k) * 256 + tn + c4];
        T[k][c4] = v.x; T[k][c4 + 1] = v.y; T[k][c4 + 2] = v.z; T[k][c4 + 3] = v.w;
    }
    __syncthreads();
#pragma unroll
    for (int j = 0; j < 4; ++j) {
        const int idx = t + 256 * j;
        const int n = idx >> 4, q = (idx & 15) * 4;
        unsigned short hh[4], ll[4];
#pragma unroll
        for (int i = 0; i < 4; ++i) {
            const float f = T[q + i][n];
            hh[i] = f2h(f);
            ll[i] = f2h(f - h2f(hh[i]));
        }
        uint2 hp, lp;
        hp.x = (unsigned)hh[0] | ((unsigned)hh[1] << 16);
        hp.y = (unsigned)hh[2] | ((unsigned)hh[3] << 16);
        lp.x = (unsigned)ll[0] | ((unsigned)ll[1] << 16);
        lp.y = (unsigned)ll[2] | ((unsigned)ll[3] << 16);
        unsigned short* row = Bt + (size_t)(tn + n) * 768;
        *(uint2*)&row[tk + q]       = hp;   // Bh
        *(uint2*)&row[256 + tk + q] = lp;   // Bl
        *(uint2*)&row[512 + tk + q] = hp;   // Bh (pairs with Al, FT only)
    }
}

// Pre-split x[M][256] fp32 -> xh/xl f16 planes (zero pad rows >= N).
__global__ void tg_splitX(const float* __restrict__ x,
                          unsigned short* __restrict__ xh,
                          unsigned short* __restrict__ xl, int N, int Mpad)
{
    const int idx = blockIdx.x * 256 + threadIdx.x;
    const int r = idx >> 6, c4 = (idx & 63) * 4;
    if (r >= Mpad) return;
    ushort4 oh = {0, 0, 0, 0}, ol = {0, 0, 0, 0};
    if (r < N) {
        const float4 v = *(const float4*)&x[(size_t)r * 256 + c4];
        oh.x = f2h(v.x); ol.x = f2h(v.x - h2f(oh.x));
        oh.y = f2h(v.y); ol.y = f2h(v.y - h2f(oh.y));
        oh.z = f2h(v.z); ol.z = f2h(v.z - h2f(oh.z));
        oh.w = f2h(v.w); ol.w = f2h(v.w - h2f(oh.w));
    }
    *(ushort4*)&xh[(size_t)r * 256 + c4] = oh;
    *(ushort4*)&xl[(size_t)r * 256 + c4] = ol;
}

// m97-style GEMM: C[128x128 tile] = A'[M x 64*nc] @ B'[.. x 128cols].
// Chunk c: plane = (c<8) ? Ph : Pl, A k-offset (c&3)*64, B' k-offset c*64.
//   FT  (mode 0): nc=12, out = relu(acc+bias) -> f16 hi/lo planes, rows < M.
//   GCN (mode 1): nc=8 (Pl unused), out = f16(acc * rowscale[row]).
__global__ __launch_bounds__(256, 3)
void tg_gemm(const unsigned short* __restrict__ Ph,
             const unsigned short* __restrict__ Pl,
             const unsigned short* __restrict__ Bt,
             const float* __restrict__ bias, const float* __restrict__ rowscale,
             unsigned short* __restrict__ outHi, unsigned short* __restrict__ outLo,
             int M, int mode, int nc)
{
    __shared__ unsigned short sA[128 * 64], sB[128 * 64];  // 16 KB each

    const int t = threadIdx.x;
    const int w = t >> 6, lane = t & 63;
    const int quad = lane >> 4, l16 = lane & 15;
    const int wr = w >> 1, wc = w & 1;
    const int row0 = blockIdx.x * 128;
    const int col0 = blockIdx.y * 128;

    floatx4 acc[4][4];
#pragma unroll
    for (int i = 0; i < 4; ++i)
#pragma unroll
        for (int j = 0; j < 4; ++j) acc[i][j] = (floatx4){0.f, 0.f, 0.f, 0.f};

    // staging decode: 8 lanes per row, slot (lane&7) holds source kg = slot^(row&7)
    const int srow = lane >> 3;
    const int kgx  = (lane & 7) ^ srow;
    const int rsw  = l16 & 7;

    for (int c = 0; c < nc; ++c) {
        const unsigned short* Pa = (c < 8) ? Ph : Pl;
        const int ka = (c & 3) * 64;
        const int kb = c * 64;
        if (c) __syncthreads();
#pragma unroll
        for (int i = 0; i < 4; ++i) {
            const int r = w * 32 + i * 8;       // wave-uniform LDS row base
            gl_lds16(Pa + (size_t)(row0 + r + srow) * 256 + ka + kgx * 8, &sA[r * 64]);
            gl_lds16(Bt + (size_t)(col0 + r + srow) * 768 + kb + kgx * 8, &sB[r * 64]);
        }
        __syncthreads();

#pragma unroll
        for (int ks = 0; ks < 2; ++ks) {
            const int kq = ks * 4 + quad;
            half8 af[4], bfr[4];
#pragma unroll
            for (int rt = 0; rt < 4; ++rt) {
                const int r = wr * 64 + rt * 16 + l16;
                af[rt] = *(const half8*)&sA[r * 64 + ((kq ^ rsw) * 8)];
            }
#pragma unroll
            for (int ct = 0; ct < 4; ++ct) {
                const int n = wc * 64 + ct * 16 + l16;
                bfr[ct] = *(const half8*)&sB[n * 64 + ((kq ^ rsw) * 8)];
            }
#pragma unroll
            for (int ct = 0; ct < 4; ++ct)
#pragma unroll
                for (int rt = 0; rt < 4; ++rt)
                    acc[rt][ct] = __builtin_amdgcn_mfma_f32_16x16x32_f16(
                        af[rt], bfr[ct], acc[rt][ct], 0, 0, 0);
        }
    }

    if (mode == 1) {   // GCN: f16(acc * rowscale)
#pragma unroll
        for (int rt = 0; rt < 4; ++rt) {
#pragma unroll
            for (int i = 0; i < 4; ++i) {
                const int gr = row0 + wr * 64 + rt * 16 + quad * 4 + i;
                const float s = rowscale[gr];
#pragma unroll
                for (int ct = 0; ct < 4; ++ct) {
                    const int gc = col0 + wc * 64 + ct * 16 + l16;
                    outHi[(size_t)gr * 256 + gc] = f2h(acc[rt][ct][i] * s);
                }
            }
        }
    } else {           // FT: relu(acc+bias) -> f16 hi/lo planes
#pragma unroll
        for (int rt = 0; rt < 4; ++rt) {
#pragma unroll
            for (int i = 0; i < 4; ++i) {
                const int gr = row0 + wr * 64 + rt * 16 + quad * 4 + i;
                if (gr >= M) continue;
#pragma unroll
                for (int ct = 0; ct < 4; ++ct) {
                    const int gc = col0 + wc * 64 + ct * 16 + l16;
                    float v = fmaxf(acc[rt][ct][i] + bias[gc], 0.f);
                    const unsigned short hi = f2h(v);
                    outHi[(size_t)gr * 256 + gc] = hi;
                    outLo[(size_t)gr * 256 + gc] = f2h(v - h2f(hi));
                }
            }
        }
    }
}

// LayerNorm + PE: reads f16 hi/lo pair, writes SINGLE f16 plane (into hh).
__global__ void tg_ln_pe(unsigned short* __restrict__ hh, const unsigned short* __restrict__ hl,
                         const float* __restrict__ g, const float* __restrict__ b, int N)
{
    const int gt = blockIdx.x * blockDim.x + threadIdx.x;
    const int row = gt >> 6;
    const int lane = threadIdx.x & 63;
    if (row >= N) return;
    const int c = lane * 4;
    unsigned short* hp = hh + (size_t)row * 256 + c;
    const ushort4 vh = *(const ushort4*)hp;
    const ushort4 vl = *(const ushort4*)(hl + (size_t)row * 256 + c);
    const float v0 = h2f(vh.x) + h2f(vl.x);
    const float v1 = h2f(vh.y) + h2f(vl.y);
    const float v2 = h2f(vh.z) + h2f(vl.z);
    const float v3 = h2f(vh.w) + h2f(vl.w);
    float s = v0 + v1 + v2 + v3;
#pragma unroll
    for (int m = 1; m < 64; m <<= 1) s += __shfl_xor(s, m, 64);
    const float mu = s * (1.f / 256.f);
    const float d0 = v0 - mu, d1 = v1 - mu, d2 = v2 - mu, d3 = v3 - mu;
    float q = d0 * d0 + d1 * d1 + d2 * d2 + d3 * d3;
#pragma unroll
    for (int m = 1; m < 64; m <<= 1) q += __shfl_xor(q, m, 64);
    const float rstd = 1.f / sqrtf(q * (1.f / 256.f) + 1e-5f);

    const float4 gg = *(const float4*)&g[c];
    const float4 bb = *(const float4*)&b[c];
    const float cexp = -0.035977892078031970f;  // -log(10000)/256
    const float fn = (float)row;
    const float div0 = expf((float)c * cexp);
    const float div1 = expf((float)(c + 2) * cexp);
    const float a0 = fn * div0;
    const float a1 = fn * div1;
    ushort4 o;
    o.x = f2h(d0 * rstd * gg.x + bb.x + sinf(a0));
    o.y = f2h(d1 * rstd * gg.y + bb.y + cosf(a0));
    o.z = f2h(d2 * rstd * gg.z + bb.z + sinf(a1));
    o.w = f2h(d3 * rstd * gg.w + bb.w + cosf(a1));
    *(ushort4*)hp = o;
}

__global__ void tg_count(const int* __restrict__ dst, int* __restrict__ deg, int E)
{
    const int e = blockIdx.x * blockDim.x + threadIdx.x;
    if (e < E) atomicAdd(&deg[dst[e]], 1);
}

__global__ void tg_dinv(const int* __restrict__ deg, float* __restrict__ dinv, int N)
{
    const int i = blockIdx.x * blockDim.x + threadIdx.x;
    if (i < N) dinv[i] = 1.f / sqrtf((float)(deg[i] + 1));  // +1 self-loop
}

__global__ void tg_scan1(const int* __restrict__ cnt, int* __restrict__ out,
                         int* __restrict__ sums, int N)
{
    __shared__ int tmp[1024];
    const int t = threadIdx.x;
    const int gid = blockIdx.x * 1024 + t;
    const int v = (gid < N) ? cnt[gid] : 0;
    tmp[t] = v;
    __syncthreads();
    for (int o = 1; o < 1024; o <<= 1) {
        const int add = (t >= o) ? tmp[t - o] : 0;
        __syncthreads();
        tmp[t] += add;
        __syncthreads();
    }
    if (gid < N) out[gid] = tmp[t] - v;
    if (t == 1023) sums[blockIdx.x] = tmp[t];
}

__global__ void tg_scan2(int* __restrict__ sums, int nb)
{
    __shared__ int tmp[1024];
    const int t = threadIdx.x;
    const int v = (t < nb) ? sums[t] : 0;
    tmp[t] = v;
    __syncthreads();
    for (int o = 1; o < 1024; o <<= 1) {
        const int add = (t >= o) ? tmp[t - o] : 0;
        __syncthreads();
        tmp[t] += add;
        __syncthreads();
    }
    if (t < nb) sums[t] = tmp[t] - v;
}

__global__ void tg_scan3(int* __restrict__ rowptr, const int* __restrict__ offs,
                         int N, int E)
{
    const int gid = blockIdx.x * 1024 + threadIdx.x;
    if (gid < N) rowptr[gid] += offs[gid >> 10];
    else if (gid == N) rowptr[N] = E;
}

__global__ void tg_fill(const int* __restrict__ src, const int* __restrict__ dst,
                        const int* __restrict__ rowptr, int* __restrict__ cursor,
                        int* __restrict__ col, int E)
{
    const int e = blockIdx.x * blockDim.x + threadIdx.x;
    if (e >= E) return;
    const int d = dst[e];
    const int p = atomicAdd(&cursor[d], 1);
    col[rowptr[d] + p] = src[e];
}

// out = relu(dinv[i]*(hwp[i] + sum hwp[src]) + bias): f16 in, single f16 out.
__global__ void tg_aggregate_h(const unsigned short* __restrict__ hwpb,
                               const int* __restrict__ rowptr, const int* __restrict__ col,
                               const float* __restrict__ dinv, const float* __restrict__ bias,
                               unsigned short* __restrict__ hh, int N)
{
    const int row = (blockIdx.x * blockDim.x + threadIdx.x) >> 6;
    if (row >= N) return;
    const int lane = threadIdx.x & 63;
    const int c = lane * 4;
    const unsigned short* base = hwpb + c;
    const ushort4 sv = *(const ushort4*)(base + (size_t)row * 256);
    float a0 = h2f(sv.x), a1 = h2f(sv.y), a2 = h2f(sv.z), a3 = h2f(sv.w);
    const int beg = rowptr[row], end = rowptr[row + 1];
    int p = beg;
    for (; p + 8 <= end; p += 8) {
        ushort4 v[8];
#pragma unroll
        for (int u = 0; u < 8; ++u)
            v[u] = *(const ushort4*)(base + (size_t)col[p + u] * 256);
#pragma unroll
        for (int u = 0; u < 8; ++u) {
            a0 += h2f(v[u].x); a1 += h2f(v[u].y);
            a2 += h2f(v[u].z); a3 += h2f(v[u].w);
        }
    }
    for (; p < end; ++p) {
        const ushort4 v = *(const ushort4*)(base + (size_t)col[p] * 256);
        a0 += h2f(v.x); a1 += h2f(v.y); a2 += h2f(v.z); a3 += h2f(v.w);
    }
    const float di = dinv[row];
    const float4 bb = *(const float4*)&bias[c];
    ushort4 o;
    o.x = f2h(fmaxf(di * a0 + bb.x, 0.f));
    o.y = f2h(fmaxf(di * a1 + bb.y, 0.f));
    o.z = f2h(fmaxf(di * a2 + bb.z, 0.f));
    o.w = f2h(fmaxf(di * a3 + bb.w, 0.f));
    *(ushort4*)&hh[(size_t)row * 256 + c] = o;
}

__global__ void tg_ranges(const int* __restrict__ batch, int* __restrict__ starts,
                          int N, int G)
{
    const int g = blockIdx.x * blockDim.x + threadIdx.x;
    if (g > G) return;
    int lo = 0, hi = N;
    while (lo < hi) {
        const int mid = (lo + hi) >> 1;
        if (batch[mid] < g) lo = mid + 1; else hi = mid;
    }
    starts[g] = lo;
}

// Mean-pool: block per graph, 4 waves split rows, lane owns 4 channels.
__global__ void tg_pool(const unsigned short* __restrict__ hh,
                        const int* __restrict__ starts, float* __restrict__ pooled, int G)
{
    __shared__ float sh[4][64][4];
    const int g = blockIdx.x;
    const int t = threadIdx.x;
    const int wv = t >> 6, lane = t & 63;
    const int c = lane * 4;
    const int beg = starts[g], end = starts[g + 1];
    float s0 = 0.f, s1 = 0.f, s2 = 0.f, s3 = 0.f;
    for (int r = beg + wv; r < end; r += 4) {
        const ushort4 vh = *(const ushort4*)&hh[(size_t)r * 256 + c];
        s0 += h2f(vh.x); s1 += h2f(vh.y); s2 += h2f(vh.z); s3 += h2f(vh.w);
    }
    sh[wv][lane][0] = s0; sh[wv][lane][1] = s1;
    sh[wv][lane][2] = s2; sh[wv][lane][3] = s3;
    __syncthreads();
    if (t < 64) {
        const float inv = 1.f / fmaxf((float)(end - beg), 1.f);
        float4 o;
        o.x = (sh[0][t][0] + sh[1][t][0] + sh[2][t][0] + sh[3][t][0]) * inv;
        o.y = (sh[0][t][1] + sh[1][t][1] + sh[2][t][1] + sh[3][t][1]) * inv;
        o.z = (sh[0][t][2] + sh[1][t][2] + sh[2][t][2] + sh[3][t][2]) * inv;
        o.w = (sh[0][t][3] + sh[1][t][3] + sh[2][t][3] + sh[3][t][3]) * inv;
        *(float4*)&pooled[(size_t)g * 256 + t * 4] = o;
    }
}

__global__ void tg_mlp(const float* __restrict__ A, const float* __restrict__ B,
                       const float* __restrict__ bias, float* __restrict__ Cout,
                       int M, int K, int Nc, int do_relu)
{
    const int idx = blockIdx.x * blockDim.x + threadIdx.x;
    if (idx >= M * Nc) return;
    const int m = idx / Nc;
    const int n = idx - m * Nc;
    float acc = 0.f;
    for (int k = 0; k < K; ++k) acc += A[(size_t)m * K + k] * B[(size_t)k * Nc + n];
    acc += bias[n];
    Cout[idx] = do_relu ? fmaxf(acc, 0.f) : acc;
}

extern "C" void kernel_launch(void* const* d_in, const int* in_sizes, int n_in,
                              void* d_out, int out_size, void* d_ws, size_t ws_size,
                              hipStream_t stream)
{
    const float* x    = (const float*)d_in[0];
    const float* W_ft = (const float*)d_in[1];
    const float* b_ft = (const float*)d_in[2];
    const float* ln_g = (const float*)d_in[3];
    const float* ln_b = (const float*)d_in[4];
    const float* W_g[3] = {(const float*)d_in[5], (const float*)d_in[7], (const float*)d_in[9]};
    const float* b_g[3] = {(const float*)d_in[6], (const float*)d_in[8], (const float*)d_in[10]};
    const float* W_c0 = (const float*)d_in[11];
    const float* b_c0 = (const float*)d_in[12];
    const float* W_c1 = (const float*)d_in[13];
    const float* b_c1 = (const float*)d_in[14];
    const float* W_c2 = (const float*)d_in[15];
    const float* b_c2 = (const float*)d_in[16];
    const int*   edge  = (const int*)d_in[17];
    const int*   batch = (const int*)d_in[18];

    const int N    = in_sizes[18];        // 100000
    const int E    = in_sizes[17] / 2;    // 1600000
    const int Mpad = (N + 127) & ~127;    // 100096
    const int H2   = in_sizes[14];        // 128
    const int Cc   = in_sizes[15] / H2;   // 4
    const int G    = out_size / Cc;       // 512

    const int* srcI = edge;
    const int* dstI = edge + E;

    size_t off = 0;
    auto alloc = [&](size_t bytes) {
        char* p = (char*)d_ws + off;
        off = (off + bytes + 255) & ~(size_t)255;
        return p;
    };
    unsigned short* hh   = (unsigned short*)alloc((size_t)Mpad * 256 * 2);
    unsigned short* hl   = (unsigned short*)alloc((size_t)Mpad * 256 * 2);
    unsigned short* hwpb = (unsigned short*)alloc((size_t)Mpad * 256 * 2); // aliases xh
    unsigned short* xl   = (unsigned short*)alloc((size_t)Mpad * 256 * 2);
    unsigned short* xh   = hwpb;  // x hi-plane lives in hwpb until FT GEMM done
    float* dinv   = (float*)alloc((size_t)Mpad * 4);
    int*   deg    = (int*)alloc((size_t)Mpad * 4);
    int*   rowptr = (int*)alloc((size_t)(N + 1) * 4);
    int*   cursor = (int*)alloc((size_t)N * 4);
    int*   col    = (int*)alloc((size_t)E * 4);
    int*   bsums  = (int*)alloc(1024 * 4);
    int*   starts = (int*)alloc((size_t)(G + 1) * 4);
    float* pooled = (float*)alloc((size_t)G * 256 * 4);
    float* z0     = (float*)alloc((size_t)G * 256 * 4);
    float* z1     = (float*)alloc((size_t)G * H2 * 4);
    unsigned short* Bt[4];
    for (int i = 0; i < 4; ++i)
        Bt[i] = (unsigned short*)alloc((size_t)256 * 768 * 2);
    (void)ws_size; (void)n_in;

    hipMemsetAsync(deg, 0, (size_t)Mpad * 4, stream);
    hipMemsetAsync(cursor, 0, (size_t)N * 4, stream);
    // zero pad rows of h planes (read by GCN GEMM A staging)
    hipMemsetAsync(hh + (size_t)N * 256, 0, (size_t)(Mpad - N) * 256 * 2, stream);
    hipMemsetAsync(hl + (size_t)N * 256, 0, (size_t)(Mpad - N) * 256 * 2, stream);

    // 0. weight prep + x split
    tg_splitB<<<dim3(4, 4, 4), dim3(256), 0, stream>>>(
        W_ft, W_g[0], W_g[1], W_g[2], Bt[0], Bt[1], Bt[2], Bt[3]);
    tg_splitX<<<dim3(Mpad / 4), dim3(256), 0, stream>>>(x, xh, xl, N, Mpad);

    const dim3 GG(Mpad / 128, 2);
    // 1. feature transform -> h f16 hi/lo pair (K'=768: Ah.Bh + Ah.Bl + Al.Bh)
    tg_gemm<<<GG, dim3(256), 0, stream>>>(xh, xl, Bt[0], b_ft, nullptr, hh, hl, N, 0, 12);
    // 2. LayerNorm + PE: pair -> single f16 plane (in hh)
    tg_ln_pe<<<dim3((N + 3) / 4), dim3(256), 0, stream>>>(hh, hl, ln_g, ln_b, N);
    // 3. degrees + CSR build (rows = dst, cols = src)
    tg_count<<<dim3((E + 255) / 256), dim3(256), 0, stream>>>(dstI, deg, E);
    tg_dinv<<<dim3((Mpad + 255) / 256), dim3(256), 0, stream>>>(deg, dinv, Mpad);
    const int NB = (N + 1023) / 1024;
    tg_scan1<<<dim3(NB), dim3(1024), 0, stream>>>(deg, rowptr, bsums, N);
    tg_scan2<<<dim3(1), dim3(1024), 0, stream>>>(bsums, NB);
    tg_scan3<<<dim3((N + 1024) / 1024), dim3(1024), 0, stream>>>(rowptr, bsums, N, E);
    tg_fill<<<dim3((E + 255) / 256), dim3(256), 0, stream>>>(srcI, dstI, rowptr, cursor, col, E);
    // 4. GCN layers: hwpb = f16((h@W)*dinv) with K'=512 single-plane A;
    //    h = relu(dinv*(hwp[i]+sum hwp[src]) + b) single f16 plane
    for (int l = 0; l < 3; ++l) {
        tg_gemm<<<GG, dim3(256), 0, stream>>>(hh, hh, Bt[l + 1], nullptr, dinv,
                                              hwpb, nullptr, Mpad, 1, 8);
        tg_aggregate_h<<<dim3((N + 3) / 4), dim3(256), 0, stream>>>(hwpb, rowptr, col, dinv,
                                                                    b_g[l], hh, N);
    }
    // 5. per-graph mean pool
    tg_ranges<<<dim3((G + 256) / 256), dim3(256), 0, stream>>>(batch, starts, N, G);
    tg_pool<<<dim3(G), dim3(256), 0, stream>>>(hh, starts, pooled, G);
    // 6. classifier MLP
    tg_mlp<<<dim3((G * 256 + 255) / 256), dim3(256), 0, stream>>>(pooled, W_c0, b_c0, z0, G, 256, 256, 1);
    tg_mlp<<<dim3((G * H2 + 255) / 256), dim3(256), 0, stream>>>(z0, W_c1, b_c1, z1, G, 256, H2, 1);
    tg_mlp<<<dim3((G * Cc + 255) / 256), dim3(256), 0, stream>>>(z1, W_c2, b_c2, (float*)d_out, G, H2, Cc, 0);
}